// Round 1
// baseline (164.011 us; speedup 1.0000x reference)
//
#include <hip/hip_runtime.h>
#include <hip/hip_bf16.h>

// B=32, C=512, H=W=32, HW=1024
// out[b,j,s] = relu(x[b,j,s] + 0.1 * sum_k attnT[b,j,k] * x[b,k,s])
// attnT[b,j,k] = exp(-(m_j-m_k)^2) / sum_i exp(-(m_j-m_i)^2),  m = spatial mean

typedef __bf16 bf16x8 __attribute__((ext_vector_type(8)));
typedef __bf16 bf16x4 __attribute__((ext_vector_type(4)));
typedef float floatx4 __attribute__((ext_vector_type(4)));

// ---------------- kernel 1: per-(b,c) spatial mean ----------------
// one wave per row of 1024 floats; block = 4 waves
__global__ __launch_bounds__(256) void mean_kernel(const float* __restrict__ x,
                                                   float* __restrict__ xm) {
    int row  = blockIdx.x * 4 + (threadIdx.x >> 6);   // b*512 + c
    int lane = threadIdx.x & 63;
    const float4* p = (const float4*)(x + (size_t)row * 1024);
    float s = 0.0f;
#pragma unroll
    for (int i = 0; i < 4; i++) {
        float4 v = p[lane + i * 64];
        s += v.x + v.y + v.z + v.w;
    }
#pragma unroll
    for (int off = 32; off; off >>= 1) s += __shfl_down(s, off);
    if (lane == 0) xm[row] = s * (1.0f / 1024.0f);
}

// ---------------- kernel 2: transpose + bf16 cast -----------------
// x[b,c,s] (fp32) -> xT[b,s,c] (bf16); 64x64 tiles through LDS
__global__ __launch_bounds__(256) void transpose_kernel(const float* __restrict__ x,
                                                        __bf16* __restrict__ xT) {
    int b  = blockIdx.z;
    int c0 = blockIdx.y * 64;
    int s0 = blockIdx.x * 64;
    __shared__ float tile[64][65];
    const float* xb = x + (size_t)b * 512 * 1024;
    int t = threadIdx.x;
#pragma unroll
    for (int i = 0; i < 4; i++) {
        int f  = t + i * 256;        // float4 id 0..1023
        int r  = f >> 4;             // c row 0..63
        int c4 = (f & 15) * 4;       // s col
        float4 v = *(const float4*)&xb[(size_t)(c0 + r) * 1024 + s0 + c4];
        tile[r][c4 + 0] = v.x; tile[r][c4 + 1] = v.y;
        tile[r][c4 + 2] = v.z; tile[r][c4 + 3] = v.w;
    }
    __syncthreads();
    __bf16* o = xT + (size_t)b * 1024 * 512;
#pragma unroll
    for (int i = 0; i < 4; i++) {
        int q  = t + i * 256;        // bf16x4 id 0..1023
        int sr = q >> 4;             // s row 0..63
        int c4 = (q & 15) * 4;       // c col
        bf16x4 w;
#pragma unroll
        for (int e = 0; e < 4; e++) w[e] = (__bf16)tile[c4 + e][sr];
        *(bf16x4*)&o[(size_t)(s0 + sr) * 512 + c0 + c4] = w;
    }
}

// ---------------- kernel 3: softmax attn^T (bf16) -----------------
// one wave per (b,j); denom over k via butterfly reduce
__global__ __launch_bounds__(256) void attn_kernel(const float* __restrict__ xm,
                                                   __bf16* __restrict__ attnT) {
    int gw   = blockIdx.x * 4 + (threadIdx.x >> 6);   // b*512 + j
    int b    = gw >> 9;
    int j    = gw & 511;
    int lane = threadIdx.x & 63;
    const float* m = xm + b * 512;
    float mj = m[j];
    float e[8];
    float s = 0.0f;
#pragma unroll
    for (int i = 0; i < 8; i++) {
        float d = mj - m[lane + i * 64];
        e[i] = __expf(-d * d);
        s += e[i];
    }
#pragma unroll
    for (int off = 32; off; off >>= 1) s += __shfl_xor(s, off);
    float inv = 1.0f / s;
    __bf16* o = attnT + (size_t)gw * 512;
#pragma unroll
    for (int i = 0; i < 8; i++) o[lane + i * 64] = (__bf16)(e[i] * inv);
}

// ---------------- kernel 4: batched GEMM + epilogue ---------------
// D[j,s] = sum_k attnT[j,k] * xT[s,k]; out = relu(x + 0.1*D)
// 128x128 tile, 4 waves, each wave 64x64 via 4x4 grid of 16x16x32 MFMA
__global__ __launch_bounds__(256) void gemm_kernel(const __bf16* __restrict__ attnT,
                                                   const __bf16* __restrict__ xT,
                                                   const float* __restrict__ x,
                                                   float* __restrict__ out) {
    int b  = blockIdx.z;
    int m0 = blockIdx.y * 128;   // j tile
    int n0 = blockIdx.x * 128;   // s tile
    const __bf16* A  = attnT + (size_t)b * 512 * 512;   // [j][k]
    const __bf16* Bm = xT    + (size_t)b * 1024 * 512;  // [s][k]
    __shared__ __bf16 As[128][40];   // +8 pad: stride 80 B -> 2-way b128 (free)
    __shared__ __bf16 Bs[128][40];
    int tid  = threadIdx.x;
    int wave = tid >> 6, lane = tid & 63;
    int wr = wave >> 1, wc = wave & 1;
    int quad = lane >> 4, l16 = lane & 15;

    floatx4 acc[4][4];
#pragma unroll
    for (int i = 0; i < 4; i++)
#pragma unroll
        for (int j = 0; j < 4; j++) acc[i][j] = (floatx4){0.f, 0.f, 0.f, 0.f};

    for (int k0 = 0; k0 < 512; k0 += 32) {
#pragma unroll
        for (int i = 0; i < 2; i++) {
            int q = tid + i * 256;        // 16B chunk id; 4 chunks/row
            int r = q >> 2, c8 = (q & 3) << 3;
            *(uint4*)&As[r][c8] = *(const uint4*)&A [(size_t)(m0 + r) * 512 + k0 + c8];
            *(uint4*)&Bs[r][c8] = *(const uint4*)&Bm[(size_t)(n0 + r) * 512 + k0 + c8];
        }
        __syncthreads();
        bf16x8 af[4], bfrag[4];
#pragma unroll
        for (int mi = 0; mi < 4; mi++)
            af[mi] = *(bf16x8*)&As[wr * 64 + mi * 16 + l16][quad * 8];
#pragma unroll
        for (int ni = 0; ni < 4; ni++)
            bfrag[ni] = *(bf16x8*)&Bs[wc * 64 + ni * 16 + l16][quad * 8];
#pragma unroll
        for (int mi = 0; mi < 4; mi++)
#pragma unroll
            for (int ni = 0; ni < 4; ni++)
                acc[mi][ni] = __builtin_amdgcn_mfma_f32_16x16x32_bf16(
                    af[mi], bfrag[ni], acc[mi][ni], 0, 0, 0);
        __syncthreads();
    }

    const float* xb = x   + (size_t)b * 512 * 1024;
    float*       ob = out + (size_t)b * 512 * 1024;
#pragma unroll
    for (int mi = 0; mi < 4; mi++)
#pragma unroll
        for (int r = 0; r < 4; r++) {
            int j = m0 + wr * 64 + mi * 16 + quad * 4 + r;
#pragma unroll
            for (int ni = 0; ni < 4; ni++) {
                int s = n0 + wc * 64 + ni * 16 + l16;
                float v = xb[(size_t)j * 1024 + s] + 0.1f * acc[mi][ni][r];
                ob[(size_t)j * 1024 + s] = fmaxf(v, 0.0f);
            }
        }
}

extern "C" void kernel_launch(void* const* d_in, const int* in_sizes, int n_in,
                              void* d_out, int out_size, void* d_ws, size_t ws_size,
                              hipStream_t stream) {
    const float* x = (const float*)d_in[0];
    float* out = (float*)d_out;
    char* ws = (char*)d_ws;
    float*  xm    = (float*)ws;                                         // 64 KB
    __bf16* attnT = (__bf16*)(ws + (64 << 10));                         // 16 MB
    __bf16* xT    = (__bf16*)(ws + (64 << 10) + (size_t)32*512*512*2);  // 33.5 MB

    mean_kernel<<<4096, 256, 0, stream>>>(x, xm);
    transpose_kernel<<<dim3(16, 8, 32), 256, 0, stream>>>(x, xT);
    attn_kernel<<<4096, 256, 0, stream>>>(xm, attnT);
    gemm_kernel<<<dim3(8, 4, 32), 256, 0, stream>>>(attnT, xT, x, out);
}

// Round 2
// 158.360 us; speedup vs baseline: 1.0357x; 1.0357x over previous
//
#include <hip/hip_runtime.h>
#include <hip/hip_bf16.h>

// B=32, C=512, H=W=32, HW=1024
// out[b,j,s] = relu(x[b,j,s] + 0.1 * sum_k attnT[b,j,k] * x[b,k,s])
// attnT[b,j,k] = exp(-(m_j-m_k)^2) / sum_i exp(-(m_i-m_j)^2),  m = spatial mean

typedef __bf16 bf16x8 __attribute__((ext_vector_type(8)));
typedef float floatx4 __attribute__((ext_vector_type(4)));

__device__ __forceinline__ void async_cp16(const void* gsrc, void* ldst) {
    __builtin_amdgcn_global_load_lds(
        (const __attribute__((address_space(1))) unsigned int*)gsrc,
        (__attribute__((address_space(3))) unsigned int*)ldst,
        16, 0, 0);
}

// ---------------- kernel 1: per-(b,c) spatial mean ----------------
__global__ __launch_bounds__(256) void mean_kernel(const float* __restrict__ x,
                                                   float* __restrict__ xm) {
    int row  = blockIdx.x * 4 + (threadIdx.x >> 6);   // b*512 + c
    int lane = threadIdx.x & 63;
    const float4* p = (const float4*)(x + (size_t)row * 1024);
    float s = 0.0f;
#pragma unroll
    for (int i = 0; i < 4; i++) {
        float4 v = p[lane + i * 64];
        s += v.x + v.y + v.z + v.w;
    }
#pragma unroll
    for (int off = 32; off; off >>= 1) s += __shfl_down(s, off);
    if (lane == 0) xm[row] = s * (1.0f / 1024.0f);
}

// ---------------- kernel 2: softmax attn^T (bf16) -----------------
// one wave per (b,j); attnT[b,j,k] = exp(-(m_j-m_k)^2)/sum_i exp(-(m_i-m_j)^2)
__global__ __launch_bounds__(256) void attn_kernel(const float* __restrict__ xm,
                                                   __bf16* __restrict__ attnT) {
    int gw   = blockIdx.x * 4 + (threadIdx.x >> 6);   // b*512 + j
    int b    = gw >> 9;
    int j    = gw & 511;
    int lane = threadIdx.x & 63;
    const float* m = xm + b * 512;
    float mj = m[j];
    float e[8];
    float s = 0.0f;
#pragma unroll
    for (int i = 0; i < 8; i++) {
        float d = mj - m[lane + i * 64];
        e[i] = __expf(-d * d);
        s += e[i];
    }
#pragma unroll
    for (int off = 32; off; off >>= 1) s += __shfl_xor(s, off);
    float inv = 1.0f / s;
    __bf16* o = attnT + (size_t)gw * 512;
#pragma unroll
    for (int i = 0; i < 8; i++) o[lane + i * 64] = (__bf16)(e[i] * inv);
}

// ---------------- kernel 3: fused batched GEMM --------------------
// D[j,s] = sum_k attnT[j,k] * x[k,s]; out = relu(x + 0.1*D)
// BM=128 (j), BN=128 (s), BK=64. A: attnT via global_load_lds (2 panels of
// 64-B rows). B: x fp32 rows, transposed+bf16-cast in registers, stored to
// LDS with 16B-unit XOR swizzle u^=((s>>2)^s)&7 (bank-even writes AND reads).
__global__ __launch_bounds__(256, 3) void gemm_kernel(const __bf16* __restrict__ attnT,
                                                      const float* __restrict__ x,
                                                      float* __restrict__ out) {
    int b  = blockIdx.z;
    int m0 = blockIdx.y * 128;   // j tile
    int n0 = blockIdx.x * 128;   // s tile
    const __bf16* Ab = attnT + (size_t)b * 512 * 512 + (size_t)m0 * 512;
    const float*  xb = x + (size_t)b * 512 * 1024;

    __shared__ __bf16 As[2][128][32];  // [k-half][j][k%32]  64-B rows
    __shared__ __bf16 Bs[128][64];     // [s][k] with unit-swizzle, 128-B rows

    int tid  = threadIdx.x;
    int wave = tid >> 6, lane = tid & 63;
    int wr = wave >> 1, wc = wave & 1;
    int quad = lane >> 4, l16 = lane & 15;

    // B-staging thread mapping: ko = k-octet (8 k's), sq = s-quad (4 s's)
    int ko = tid >> 5;        // 0..7
    int sq = tid & 31;        // 0..31

    floatx4 acc[4][4];
#pragma unroll
    for (int i = 0; i < 4; i++)
#pragma unroll
        for (int j = 0; j < 4; j++) acc[i][j] = (floatx4){0.f, 0.f, 0.f, 0.f};

    for (int k0 = 0; k0 < 512; k0 += 64) {
        // ---- A: async global->LDS, 4x16B per thread ----
#pragma unroll
        for (int i = 0; i < 4; i++) {
            int q = tid + i * 256;            // chunk 0..1023
            int ulow = q & 3, r = (q >> 2) & 127, p = q >> 9;
            async_cp16(Ab + (size_t)r * 512 + k0 + p * 32 + ulow * 8,
                       (char*)&As[0][0][0] + (size_t)q * 16);
        }
        // ---- B: load 8 float4 (rows k0+ko*8+kk, cols sq*4..+3) ----
        float4 f[8];
#pragma unroll
        for (int kk = 0; kk < 8; kk++)
            f[kk] = *(const float4*)&xb[(size_t)(k0 + ko * 8 + kk) * 1024 + n0 + sq * 4];
        // pack per s (4 rows), write b128 at swizzled unit
#pragma unroll
        for (int j = 0; j < 4; j++) {
            int s = sq * 4 + j;
            bf16x8 w;
            w[0] = (__bf16)f[0].x; w[1] = (__bf16)f[1].x;
            w[2] = (__bf16)f[2].x; w[3] = (__bf16)f[3].x;
            w[4] = (__bf16)f[4].x; w[5] = (__bf16)f[5].x;
            w[6] = (__bf16)f[6].x; w[7] = (__bf16)f[7].x;
            // select component j of each float4
            const float* fp = (const float*)&f[0];
#pragma unroll
            for (int kk = 0; kk < 8; kk++) w[kk] = (__bf16)fp[kk * 4 + j];
            int u = ko ^ (((s >> 2) ^ s) & 7);
            *(bf16x8*)&Bs[s][u * 8] = w;
        }
        __syncthreads();
        // ---- MFMA: two 32-k halves ----
#pragma unroll
        for (int ks = 0; ks < 2; ks++) {
            bf16x8 af[4], bfv[4];
#pragma unroll
            for (int mi = 0; mi < 4; mi++)
                af[mi] = *(bf16x8*)&As[ks][wr * 64 + mi * 16 + l16][quad * 8];
#pragma unroll
            for (int ni = 0; ni < 4; ni++) {
                int n = wc * 64 + ni * 16 + l16;
                int u = (ks * 4 + quad) ^ (((n >> 2) ^ n) & 7);
                bfv[ni] = *(bf16x8*)&Bs[n][u * 8];
            }
#pragma unroll
            for (int mi = 0; mi < 4; mi++)
#pragma unroll
                for (int ni = 0; ni < 4; ni++)
                    acc[mi][ni] = __builtin_amdgcn_mfma_f32_16x16x32_bf16(
                        af[mi], bfv[ni], acc[mi][ni], 0, 0, 0);
        }
        __syncthreads();
    }

    float* ob = out + (size_t)b * 512 * 1024;
#pragma unroll
    for (int mi = 0; mi < 4; mi++)
#pragma unroll
        for (int r = 0; r < 4; r++) {
            int j = m0 + wr * 64 + mi * 16 + quad * 4 + r;
#pragma unroll
            for (int ni = 0; ni < 4; ni++) {
                int s = n0 + wc * 64 + ni * 16 + l16;
                float v = xb[(size_t)j * 1024 + s] + 0.1f * acc[mi][ni][r];
                ob[(size_t)j * 1024 + s] = fmaxf(v, 0.0f);
            }
        }
}

extern "C" void kernel_launch(void* const* d_in, const int* in_sizes, int n_in,
                              void* d_out, int out_size, void* d_ws, size_t ws_size,
                              hipStream_t stream) {
    const float* x = (const float*)d_in[0];
    float* out = (float*)d_out;
    char* ws = (char*)d_ws;
    float*  xm    = (float*)ws;                     // 64 KB
    __bf16* attnT = (__bf16*)(ws + (64 << 10));     // 16 MB

    mean_kernel<<<4096, 256, 0, stream>>>(x, xm);
    attn_kernel<<<4096, 256, 0, stream>>>(xm, attnT);
    gemm_kernel<<<dim3(8, 4, 32), 256, 0, stream>>>(attnT, x, out);
}

// Round 3
// 152.898 us; speedup vs baseline: 1.0727x; 1.0357x over previous
//
#include <hip/hip_runtime.h>
#include <hip/hip_bf16.h>

// B=32, C=512, H=W=32, HW=1024
// out[b,j,s] = relu(x[b,j,s] + 0.1 * sum_k attnT[b,j,k] * x[b,k,s])
// attnT[b,j,k] = exp(-(m_j-m_k)^2) * invden[b,j],
// invden[b,j]  = 1 / sum_i exp(-(m_j-m_i)^2),  m = spatial mean of x
//
// A (= attnT tile) is synthesized on the fly in MFMA A-fragment layout from
// the 512 means -- no attnT materialization, no A staging, LDS holds only B.

typedef __bf16 bf16x8 __attribute__((ext_vector_type(8)));
typedef float floatx4 __attribute__((ext_vector_type(4)));

// ---------------- kernel 1: per-(b,c) spatial mean ----------------
__global__ __launch_bounds__(256) void mean_kernel(const float* __restrict__ x,
                                                   float* __restrict__ xm) {
    int row  = blockIdx.x * 4 + (threadIdx.x >> 6);   // b*512 + c
    int lane = threadIdx.x & 63;
    const float4* p = (const float4*)(x + (size_t)row * 1024);
    float s = 0.0f;
#pragma unroll
    for (int i = 0; i < 4; i++) {
        float4 v = p[lane + i * 64];
        s += v.x + v.y + v.z + v.w;
    }
#pragma unroll
    for (int off = 32; off; off >>= 1) s += __shfl_down(s, off);
    if (lane == 0) xm[row] = s * (1.0f / 1024.0f);
}

// ---------------- kernel 2: softmax inverse denominator -----------
// one wave per (b,j): invden = 1/sum_i exp(-(m_j-m_i)^2)
__global__ __launch_bounds__(256) void den_kernel(const float* __restrict__ xm,
                                                  float* __restrict__ invd) {
    int gw   = blockIdx.x * 4 + (threadIdx.x >> 6);   // b*512 + j
    int b    = gw >> 9;
    int lane = threadIdx.x & 63;
    const float* m = xm + b * 512;
    float mj = xm[gw];
    float s = 0.0f;
#pragma unroll
    for (int i = 0; i < 8; i++) {
        float d = mj - m[lane + i * 64];
        s += __expf(-d * d);
    }
#pragma unroll
    for (int off = 32; off; off >>= 1) s += __shfl_xor(s, off);
    if (lane == 0) invd[gw] = 1.0f / s;
}

// ---------------- kernel 3: fused batched GEMM --------------------
// BM=64 (j), BN=128 (s), BK=64. 4 waves in 2x2; wave tile 32x64.
// B: x fp32 rows transposed+bf16-cast in registers -> LDS (XOR-swizzled b128).
// A: exp(-(m_j-m_k)^2)*invden[j] computed per-lane directly in frag layout
//    A[m=lane&15][k=quad*8+e].
__global__ __launch_bounds__(256, 4) void gemm_kernel(const float* __restrict__ xm,
                                                      const float* __restrict__ invd,
                                                      const float* __restrict__ x,
                                                      float* __restrict__ out) {
    int b  = blockIdx.z;
    int m0 = blockIdx.y * 64;    // j tile
    int n0 = blockIdx.x * 128;   // s tile
    const float* xb  = x    + (size_t)b * 512 * 1024;
    const float* xmb = xm   + b * 512;
    const float* ivb = invd + b * 512;

    __shared__ __bf16 Bs[128][64];   // [s][k], 16B-unit XOR swizzle

    int tid  = threadIdx.x;
    int wave = tid >> 6, lane = tid & 63;
    int wr = wave >> 1, wc = wave & 1;
    int quad = lane >> 4, l16 = lane & 15;
    int ko = tid >> 5;        // 0..7  (k-octet for B staging)
    int sq = tid & 31;        // 0..31 (s-quad for B staging)

    // per-lane m_j and invden for this lane's two 16-row m-blocks
    float mjv[2], ivv[2];
#pragma unroll
    for (int mi = 0; mi < 2; mi++) {
        int j = m0 + wr * 32 + mi * 16 + l16;
        mjv[mi] = xmb[j];
        ivv[mi] = ivb[j];
    }

    floatx4 acc[2][4];
#pragma unroll
    for (int i = 0; i < 2; i++)
#pragma unroll
        for (int j = 0; j < 4; j++) acc[i][j] = (floatx4){0.f, 0.f, 0.f, 0.f};

    for (int k0 = 0; k0 < 512; k0 += 64) {
        // ---- B staging: 8 float4 (k rows ko*8..+7, s cols sq*4..+3) ----
        float4 f[8];
#pragma unroll
        for (int kk = 0; kk < 8; kk++)
            f[kk] = *(const float4*)&xb[(size_t)(k0 + ko * 8 + kk) * 1024 + n0 + sq * 4];
        const float* fp = (const float*)&f[0];
#pragma unroll
        for (int j = 0; j < 4; j++) {
            int s = sq * 4 + j;
            bf16x8 w;
#pragma unroll
            for (int kk = 0; kk < 8; kk++) w[kk] = (__bf16)fp[kk * 4 + j];
            int u = ko ^ (((s >> 2) ^ s) & 7);
            *(bf16x8*)&Bs[s][u * 8] = w;
        }
        // ---- A frags on the fly (independent of LDS; overlaps barrier) ----
        bf16x8 af[2][2];
#pragma unroll
        for (int ks = 0; ks < 2; ks++) {
            const float* mkp = &xmb[k0 + ks * 32 + quad * 8];
            float4 mk0 = *(const float4*)mkp;
            float4 mk1 = *(const float4*)(mkp + 4);
            float mkv[8] = {mk0.x, mk0.y, mk0.z, mk0.w, mk1.x, mk1.y, mk1.z, mk1.w};
#pragma unroll
            for (int mi = 0; mi < 2; mi++) {
                float mj = mjv[mi], iv = ivv[mi];
#pragma unroll
                for (int e = 0; e < 8; e++) {
                    float d = mj - mkv[e];
                    af[mi][ks][e] = (__bf16)(__expf(-d * d) * iv);
                }
            }
        }
        __syncthreads();
        // ---- MFMA ----
#pragma unroll
        for (int ks = 0; ks < 2; ks++) {
            bf16x8 bfv[4];
#pragma unroll
            for (int ni = 0; ni < 4; ni++) {
                int n = wc * 64 + ni * 16 + l16;
                int u = (ks * 4 + quad) ^ (((n >> 2) ^ n) & 7);
                bfv[ni] = *(bf16x8*)&Bs[n][u * 8];
            }
#pragma unroll
            for (int mi = 0; mi < 2; mi++)
#pragma unroll
                for (int ni = 0; ni < 4; ni++)
                    acc[mi][ni] = __builtin_amdgcn_mfma_f32_16x16x32_bf16(
                        af[mi][ks], bfv[ni], acc[mi][ni], 0, 0, 0);
        }
        __syncthreads();
    }

    float* ob = out + (size_t)b * 512 * 1024;
#pragma unroll
    for (int mi = 0; mi < 2; mi++)
#pragma unroll
        for (int r = 0; r < 4; r++) {
            int j = m0 + wr * 32 + mi * 16 + quad * 4 + r;
#pragma unroll
            for (int ni = 0; ni < 4; ni++) {
                int s = n0 + wc * 64 + ni * 16 + l16;
                float v = xb[(size_t)j * 1024 + s] + 0.1f * acc[mi][ni][r];
                ob[(size_t)j * 1024 + s] = fmaxf(v, 0.0f);
            }
        }
}

extern "C" void kernel_launch(void* const* d_in, const int* in_sizes, int n_in,
                              void* d_out, int out_size, void* d_ws, size_t ws_size,
                              hipStream_t stream) {
    const float* x = (const float*)d_in[0];
    float* out = (float*)d_out;
    char* ws = (char*)d_ws;
    float* xm   = (float*)ws;                    // 64 KB
    float* invd = (float*)(ws + (64 << 10));     // 64 KB

    mean_kernel<<<4096, 256, 0, stream>>>(x, xm);
    den_kernel<<<4096, 256, 0, stream>>>(xm, invd);
    gemm_kernel<<<dim3(8, 8, 32), 256, 0, stream>>>(xm, invd, x, out);
}